// Round 5
// baseline (276.637 us; speedup 1.0000x reference)
//
#include <hip/hip_runtime.h>
#include <stdint.h>

typedef unsigned short u16;
typedef __attribute__((ext_vector_type(8))) short bf16x8;
typedef __attribute__((ext_vector_type(4))) float f32x4;

__device__ __forceinline__ u16 f2bf(float f) {
    union { float f; uint32_t u; } v; v.f = f;
    uint32_t u = v.u + 0x7fffu + ((v.u >> 16) & 1u);
    return (u16)(u >> 16);
}
__device__ __forceinline__ float bf2f(u16 s) {
    union { uint32_t u; float f; } v; v.u = ((uint32_t)s) << 16;
    return v.f;
}
// fast positive-value pack: round-half-up (bias only on exact ties)
__device__ __forceinline__ uint32_t packbf(float a, float b) {
    union { float f; uint32_t u; } ua, ub; ua.f = a; ub.f = b;
    return ((ua.u + 0x8000u) >> 16) | ((ub.u + 0x8000u) & 0xffff0000u);
}

__device__ __forceinline__ void gld16(const void* g, void* l) {
    __builtin_amdgcn_global_load_lds((const __attribute__((address_space(1))) void*)g,
                                     (__attribute__((address_space(3))) void*)l,
                                     16, 0, 0);
}

// in-place cross-lane swap: a.row1<->b.row0, a.row3<->b.row2 (rows = 16-lane groups)
__device__ __forceinline__ void plswap16(uint32_t& a, uint32_t& b) {
    asm volatile("v_permlane16_swap_b32 %0, %1" : "+v"(a), "+v"(b));
}

// ---------------- pack kernels ----------------

__global__ void cvt_bf16_kernel(const float* __restrict__ s, u16* __restrict__ d, int n4) {
    int i = blockIdx.x * blockDim.x + threadIdx.x;
    const int stride = gridDim.x * blockDim.x;
    for (; i < n4; i += stride) {
        float4 v = ((const float4*)s)[i];
        ushort4 o;
        o.x = f2bf(v.x); o.y = f2bf(v.y); o.z = f2bf(v.z); o.w = f2bf(v.w);
        ((ushort4*)d)[i] = o;
    }
}

// dst[d][k] = src[k][d], both 1024x1024
__global__ void transpose_bf16_kernel(const float* __restrict__ src, u16* __restrict__ dst) {
    __shared__ float tile[32][33];
    const int tx = threadIdx.x, ty = threadIdx.y;
    const int bx = blockIdx.x * 32, by = blockIdx.y * 32;
#pragma unroll
    for (int i = ty; i < 32; i += 8)
        tile[i][tx] = src[(size_t)(by + i) * 1024 + bx + tx];
    __syncthreads();
#pragma unroll
    for (int i = ty; i < 32; i += 8)
        dst[(size_t)(bx + i) * 1024 + by + tx] = f2bf(tile[tx][i]);
}

// ---------------- GEMM (128x128 tile, BK=32, 4 waves) ----------------

template <int EPI>
__global__ __launch_bounds__(256) void gemm128(
    const u16* __restrict__ A, const u16* __restrict__ Bt,
    const float* __restrict__ bias0, const float* __restrict__ bias1,
    const float* __restrict__ bias2,
    u16* __restrict__ o_q, u16* __restrict__ o_k, u16* __restrict__ o_vt,
    float* __restrict__ o_f)
{
    constexpr int K = 1024;
    __shared__ u16 As[128 * 32];
    __shared__ u16 Bs[128 * 32];
    const int t = threadIdx.x;
    const int lane = t & 63, w = t >> 6;
    const int wm = w >> 1, wn = w & 1;
    const int g = lane >> 4, r = lane & 15;
    const int mbase = blockIdx.y * 128, nbase = blockIdx.x * 128;

    const f32x4 zero4 = {0.f, 0.f, 0.f, 0.f};
    f32x4 acc[4][4];
#pragma unroll
    for (int m = 0; m < 4; ++m)
#pragma unroll
        for (int n = 0; n < 4; ++n) acc[m][n] = zero4;

    for (int k0 = 0; k0 < K; k0 += 32) {
#pragma unroll
        for (int i = 0; i < 2; ++i) {
            const int base = i * 256 + (w << 6);
            const int idx = base + lane;
            const int row = idx >> 2, cc = (idx & 3) << 3;
            gld16(A + (size_t)(mbase + row) * K + k0 + cc, (char*)As + base * 16);
            gld16(Bt + (size_t)(nbase + row) * K + k0 + cc, (char*)Bs + base * 16);
        }
        __syncthreads();

        bf16x8 af[4], bfr[4];
#pragma unroll
        for (int m = 0; m < 4; ++m)
            af[m] = *(const bf16x8*)&As[(wm * 64 + m * 16 + r) * 32 + g * 8];
#pragma unroll
        for (int n = 0; n < 4; ++n)
            bfr[n] = *(const bf16x8*)&Bs[(wn * 64 + n * 16 + r) * 32 + g * 8];
        __builtin_amdgcn_s_setprio(1);
#pragma unroll
        for (int m = 0; m < 4; ++m)
#pragma unroll
            for (int n = 0; n < 4; ++n)
                acc[m][n] = __builtin_amdgcn_mfma_f32_16x16x32_bf16(af[m], bfr[n], acc[m][n], 0, 0, 0);
        __builtin_amdgcn_s_setprio(0);
        __syncthreads();
    }

#pragma unroll
    for (int m = 0; m < 4; ++m) {
#pragma unroll
        for (int n = 0; n < 4; ++n) {
            const int c = nbase + wn * 64 + n * 16 + r;
#pragma unroll
            for (int j = 0; j < 4; ++j) {
                const int rr = mbase + wm * 64 + m * 16 + g * 4 + j;
                const float y = acc[m][n][j];
                if (EPI == 0) {
                    const int which = c >> 10, d = c & 1023;
                    const int b = rr >> 11, l = rr & 2047;
                    const int h = d >> 6, dd = d & 63;
                    const size_t bh = (size_t)(b * 16 + h);
                    if (which == 0) {
                        o_q[(bh * 2048 + l) * 64 + dd] = f2bf((y + bias0[d]) * 0.125f);
                    } else if (which == 1) {
                        o_k[(bh * 2048 + l) * 64 + dd] = f2bf(y + bias1[d]);
                    } else {
                        o_vt[(bh * 64 + dd) * 2048 + l] = f2bf(y + bias2[d]);
                    }
                } else {
                    o_f[(size_t)rr * 1024 + c] = y + bias0[c];
                }
            }
        }
    }
}

// ---------------- flash attention v5: no-LDS, no-barrier, register-resident ----------------
// grid: 512 (bh = (flat&7)*4 + ((flat>>3)>>4); 4 heads per XCD share bond via L2).
// block: 256 = 4 independent waves; wave w owns 32 q-rows. The 4 waves read
// IDENTICAL K/V addresses -> L1 absorbs the amplification. Zero __syncthreads.

__device__ __forceinline__ void ldk(const u16* kp, int kt, bf16x8 (&K)[4][2]) {
#pragma unroll
    for (int kf = 0; kf < 4; ++kf)
#pragma unroll
        for (int kz = 0; kz < 2; ++kz)
            K[kf][kz] = *(const bf16x8*)(kp + (size_t)(kt + kf * 16) * 64 + kz * 32);
}
__device__ __forceinline__ void ldv(const u16* vp, int kt, bf16x8 (&V)[4][2]) {
#pragma unroll
    for (int nf = 0; nf < 4; ++nf)
#pragma unroll
        for (int kz = 0; kz < 2; ++kz)
            V[nf][kz] = *(const bf16x8*)(vp + (size_t)nf * 32768 + kt + kz * 32);
}
__device__ __forceinline__ void ldb(const u16* bp, int kt, ushort4 (&bd)[2][4]) {
#pragma unroll
    for (int qf = 0; qf < 2; ++qf)
#pragma unroll
        for (int kf = 0; kf < 4; ++kf)
            bd[qf][kf] = *(const ushort4*)(bp + qf * 32768 + kt + kf * 16);
}

__device__ __forceinline__ void compute_tile(
    const bf16x8 (&K)[4][2], const ushort4 (&bd)[2][4], const bf16x8 (&V)[4][2],
    const bf16x8 (&aq)[2][2], f32x4 (&o)[2][4], float (&sm)[2])
{
    const f32x4 zero4 = {0.f, 0.f, 0.f, 0.f};
#pragma unroll
    for (int qf = 0; qf < 2; ++qf) {
        f32x4 st[4];
#pragma unroll
        for (int kf = 0; kf < 4; ++kf) st[kf] = zero4;
        __builtin_amdgcn_s_setprio(1);
#pragma unroll
        for (int kz = 0; kz < 2; ++kz)
#pragma unroll
            for (int kf = 0; kf < 4; ++kf)
                st[kf] = __builtin_amdgcn_mfma_f32_16x16x32_bf16(K[kf][kz], aq[qf][kz], st[kf], 0, 0, 0);
        __builtin_amdgcn_s_setprio(0);
        uint32_t pkl[4], pkh[4];
#pragma unroll
        for (int kf = 0; kf < 4; ++kf) {
            const float p0 = __expf(st[kf][0] * bf2f(bd[qf][kf].x));
            const float p1 = __expf(st[kf][1] * bf2f(bd[qf][kf].y));
            const float p2 = __expf(st[kf][2] * bf2f(bd[qf][kf].z));
            const float p3 = __expf(st[kf][3] * bf2f(bd[qf][kf].w));
            sm[qf] += (p0 + p1) + (p2 + p3);
            pkl[kf] = packbf(p0, p1);
            pkh[kf] = packbf(p2, p3);
        }
        // cross-lane redistribute; resulting key order kz*32 + pg*8 + jj, pg=[0,2,1,3]
        plswap16(pkl[0], pkl[1]);
        plswap16(pkh[0], pkh[1]);
        plswap16(pkl[2], pkl[3]);
        plswap16(pkh[2], pkh[3]);
        union { uint32_t u[4]; bf16x8 v; } ap0, ap1;
        ap0.u[0] = pkl[0]; ap0.u[1] = pkh[0]; ap0.u[2] = pkl[1]; ap0.u[3] = pkh[1];
        ap1.u[0] = pkl[2]; ap1.u[1] = pkh[2]; ap1.u[2] = pkl[3]; ap1.u[3] = pkh[3];
        __builtin_amdgcn_s_setprio(1);
#pragma unroll
        for (int nf = 0; nf < 4; ++nf)
            o[qf][nf] = __builtin_amdgcn_mfma_f32_16x16x32_bf16(ap0.v, V[nf][0], o[qf][nf], 0, 0, 0);
#pragma unroll
        for (int nf = 0; nf < 4; ++nf)
            o[qf][nf] = __builtin_amdgcn_mfma_f32_16x16x32_bf16(ap1.v, V[nf][1], o[qf][nf], 0, 0, 0);
        __builtin_amdgcn_s_setprio(0);
    }
}

__global__ __launch_bounds__(256, 2) void attn_kernel(
    const u16* __restrict__ qb, const u16* __restrict__ kb,
    const u16* __restrict__ vtb, const u16* __restrict__ bondb,
    u16* __restrict__ attnout)
{
    const int t = threadIdx.x;
    const int lane = t & 63, w = t >> 6;
    const int g = lane >> 4, r = lane & 15;
    const int pg = ((g & 1) << 1) | (g >> 1);
    const int c = blockIdx.x >> 3;
    const int bh = (blockIdx.x & 7) * 4 + (c >> 4);
    const int qg = c & 15;
    const int b = bh >> 4, h = bh & 15;
    const int q0 = qg * 128 + w * 32;
    const size_t kvBase = (size_t)bh * 2048 * 64;
    // per-lane base pointers (constant per-thread parts folded once)
    const u16* kp = kb + kvBase + (size_t)r * 64 + g * 8;                     // + key*64 (+kz*32)
    const u16* vp = vtb + kvBase + (size_t)r * 2048 + pg * 8;                 // + nf*32768 + key
    const u16* bp = bondb + ((size_t)b * 2048 + q0 + r) * 2048 + g * 4;       // + qf*32768 + key

    // Q as B-operand fragments: lane gives Q[q0+qf*16+r][kz*32+g*8+jj]
    bf16x8 aq[2][2];
#pragma unroll
    for (int qf = 0; qf < 2; ++qf)
#pragma unroll
        for (int kz = 0; kz < 2; ++kz)
            aq[qf][kz] = *(const bf16x8*)&qb[kvBase + (size_t)(q0 + qf * 16 + r) * 64 + kz * 32 + g * 8];

    const f32x4 zero4 = {0.f, 0.f, 0.f, 0.f};
    f32x4 o[2][4];
#pragma unroll
    for (int qf = 0; qf < 2; ++qf)
#pragma unroll
        for (int nf = 0; nf < 4; ++nf) o[qf][nf] = zero4;
    float sm[2] = {0.f, 0.f};

    bf16x8 KA[4][2], KB[4][2], V[4][2];
    ushort4 bdA[2][4], bdB[2][4];
    ldk(kp, 0, KA);
    ldb(bp, 0, bdA);

    for (int kt = 0; kt < 2048; kt += 128) {
        // half A: compute tile kt; prefetch tile kt+64 (K,bond) and V(kt)
        ldk(kp, kt + 64, KB);
        ldb(bp, kt + 64, bdB);
        ldv(vp, kt, V);
        compute_tile(KA, bdA, V, aq, o, sm);
        // half B: compute tile kt+64; prefetch tile kt+128 (clamped) and V(kt+64)
        const int ktn = (kt + 128 < 2048) ? kt + 128 : 1984;
        ldk(kp, ktn, KA);
        ldb(bp, ktn, bdA);
        ldv(vp, kt + 64, V);
        compute_tile(KB, bdB, V, aq, o, sm);
    }

    // row sums: reduce across the 4 g-groups, redistribute via width-16 shuffle
#pragma unroll
    for (int qf = 0; qf < 2; ++qf) {
        sm[qf] += __shfl_xor(sm[qf], 16, 64);
        sm[qf] += __shfl_xor(sm[qf], 32, 64);
    }
#pragma unroll
    for (int qf = 0; qf < 2; ++qf)
#pragma unroll
        for (int j = 0; j < 4; ++j) {
            const float inv = 1.f / __shfl(sm[qf], g * 4 + j, 16);
            const size_t orow = ((size_t)b * 2048 + q0 + qf * 16 + g * 4 + j) * 1024 + h * 64;
#pragma unroll
            for (int nf = 0; nf < 4; ++nf)
                attnout[orow + nf * 16 + r] = f2bf(o[qf][nf][j] * inv);
        }
}

// ---------------- launch ----------------

extern "C" void kernel_launch(void* const* d_in, const int* in_sizes, int n_in,
                              void* d_out, int out_size, void* d_ws, size_t ws_size,
                              hipStream_t stream) {
    (void)in_sizes; (void)n_in; (void)out_size; (void)ws_size;
    const float* x    = (const float*)d_in[0];
    const float* bond = (const float*)d_in[1];
    const float* Wq   = (const float*)d_in[2];
    const float* bq   = (const float*)d_in[3];
    const float* Wk   = (const float*)d_in[4];
    const float* bk   = (const float*)d_in[5];
    const float* Wv   = (const float*)d_in[6];
    const float* bv   = (const float*)d_in[7];
    const float* Wo   = (const float*)d_in[8];
    const float* bo   = (const float*)d_in[9];
    float* out = (float*)d_out;

    char* ws = (char*)d_ws;
    u16* xb      = (u16*)(ws);
    u16* wqkvt   = (u16*)(ws + 8388608);
    u16* wot     = (u16*)(ws + 14680064);
    u16* qb      = (u16*)(ws + 16777216);
    u16* kb_     = (u16*)(ws + 25165824);
    u16* vtb     = (u16*)(ws + 33554432);
    u16* bondb   = (u16*)(ws + 41943040);
    u16* attnout = (u16*)(ws + 58720256);

    dim3 tb(32, 8);
    transpose_bf16_kernel<<<dim3(32, 32), tb, 0, stream>>>(Wq, wqkvt);
    transpose_bf16_kernel<<<dim3(32, 32), tb, 0, stream>>>(Wk, wqkvt + 1024 * 1024);
    transpose_bf16_kernel<<<dim3(32, 32), tb, 0, stream>>>(Wv, wqkvt + 2 * 1024 * 1024);
    transpose_bf16_kernel<<<dim3(32, 32), tb, 0, stream>>>(Wo, wot);
    cvt_bf16_kernel<<<1024, 256, 0, stream>>>(x, xb, 4194304 / 4);
    cvt_bf16_kernel<<<2048, 256, 0, stream>>>(bond, bondb, 8388608 / 4);

    gemm128<0><<<dim3(24, 32), 256, 0, stream>>>(xb, wqkvt, bq, bk, bv, qb, kb_, vtb, nullptr);
    attn_kernel<<<dim3(512), 256, 0, stream>>>(qb, kb_, vtb, bondb, attnout);
    gemm128<1><<<dim3(8, 32), 256, 0, stream>>>(attnout, wot, bo, nullptr, nullptr,
                                                nullptr, nullptr, nullptr, out);
}

// Round 6
// 164.340 us; speedup vs baseline: 1.6833x; 1.6833x over previous
//
#include <hip/hip_runtime.h>
#include <stdint.h>

typedef unsigned short u16;
typedef __attribute__((ext_vector_type(8))) short bf16x8;
typedef __attribute__((ext_vector_type(4))) float f32x4;

__device__ __forceinline__ u16 f2bf(float f) {
    union { float f; uint32_t u; } v; v.f = f;
    uint32_t u = v.u + 0x7fffu + ((v.u >> 16) & 1u);
    return (u16)(u >> 16);
}
// fast positive-value pack: round-half-up (bias only on exact ties)
__device__ __forceinline__ uint32_t packbf(float a, float b) {
    union { float f; uint32_t u; } ua, ub; ua.f = a; ub.f = b;
    return ((ua.u + 0x8000u) >> 16) | ((ub.u + 0x8000u) & 0xffff0000u);
}

__device__ __forceinline__ void gld16(const void* g, void* l) {
    __builtin_amdgcn_global_load_lds((const __attribute__((address_space(1))) void*)g,
                                     (__attribute__((address_space(3))) void*)l,
                                     16, 0, 0);
}

// in-place cross-lane swap: a.row1<->b.row0, a.row3<->b.row2 (rows = 16-lane groups)
__device__ __forceinline__ void plswap16(uint32_t& a, uint32_t& b) {
    asm volatile("v_permlane16_swap_b32 %0, %1" : "+v"(a), "+v"(b));
}

// ---------------- pack kernels ----------------

__global__ void cvt_bf16_kernel(const float* __restrict__ s, u16* __restrict__ d, int n4) {
    int i = blockIdx.x * blockDim.x + threadIdx.x;
    const int stride = gridDim.x * blockDim.x;
    for (; i < n4; i += stride) {
        float4 v = ((const float4*)s)[i];
        ushort4 o;
        o.x = f2bf(v.x); o.y = f2bf(v.y); o.z = f2bf(v.z); o.w = f2bf(v.w);
        ((ushort4*)d)[i] = o;
    }
}

// dst[d][k] = src[k][d]; z selects which of the 4 weight matrices
__global__ void transpose4_bf16_kernel(const float* __restrict__ Wq, const float* __restrict__ Wk,
                                       const float* __restrict__ Wv, const float* __restrict__ Wo,
                                       u16* __restrict__ dqkv, u16* __restrict__ dо) {
    __shared__ float tile[32][33];
    const int z = blockIdx.z;
    const float* src = (z == 0) ? Wq : (z == 1) ? Wk : (z == 2) ? Wv : Wo;
    u16* dst = (z < 3) ? (dqkv + (size_t)z * 1024 * 1024) : dо;
    const int tx = threadIdx.x, ty = threadIdx.y;
    const int bx = blockIdx.x * 32, by = blockIdx.y * 32;
#pragma unroll
    for (int i = ty; i < 32; i += 8)
        tile[i][tx] = src[(size_t)(by + i) * 1024 + bx + tx];
    __syncthreads();
#pragma unroll
    for (int i = ty; i < 32; i += 8)
        dst[(size_t)(bx + i) * 1024 + by + tx] = f2bf(tile[tx][i]);
}

// ---------------- GEMM (128x128 tile, BK=32, 4 waves) ----------------

template <int EPI>
__global__ __launch_bounds__(256) void gemm128(
    const u16* __restrict__ A, const u16* __restrict__ Bt,
    const float* __restrict__ bias0, const float* __restrict__ bias1,
    const float* __restrict__ bias2,
    u16* __restrict__ o_q, u16* __restrict__ o_k, u16* __restrict__ o_vt,
    float* __restrict__ o_f)
{
    constexpr int K = 1024;
    __shared__ u16 As[128 * 32];
    __shared__ u16 Bs[128 * 32];
    const int t = threadIdx.x;
    const int lane = t & 63, w = t >> 6;
    const int wm = w >> 1, wn = w & 1;
    const int g = lane >> 4, r = lane & 15;
    const int mbase = blockIdx.y * 128, nbase = blockIdx.x * 128;

    const f32x4 zero4 = {0.f, 0.f, 0.f, 0.f};
    f32x4 acc[4][4];
#pragma unroll
    for (int m = 0; m < 4; ++m)
#pragma unroll
        for (int n = 0; n < 4; ++n) acc[m][n] = zero4;

    for (int k0 = 0; k0 < K; k0 += 32) {
#pragma unroll
        for (int i = 0; i < 2; ++i) {
            const int base = i * 256 + (w << 6);
            const int idx = base + lane;
            const int row = idx >> 2, cc = (idx & 3) << 3;
            gld16(A + (size_t)(mbase + row) * K + k0 + cc, (char*)As + base * 16);
            gld16(Bt + (size_t)(nbase + row) * K + k0 + cc, (char*)Bs + base * 16);
        }
        __syncthreads();

        bf16x8 af[4], bfr[4];
#pragma unroll
        for (int m = 0; m < 4; ++m)
            af[m] = *(const bf16x8*)&As[(wm * 64 + m * 16 + r) * 32 + g * 8];
#pragma unroll
        for (int n = 0; n < 4; ++n)
            bfr[n] = *(const bf16x8*)&Bs[(wn * 64 + n * 16 + r) * 32 + g * 8];
        __builtin_amdgcn_s_setprio(1);
#pragma unroll
        for (int m = 0; m < 4; ++m)
#pragma unroll
            for (int n = 0; n < 4; ++n)
                acc[m][n] = __builtin_amdgcn_mfma_f32_16x16x32_bf16(af[m], bfr[n], acc[m][n], 0, 0, 0);
        __builtin_amdgcn_s_setprio(0);
        __syncthreads();
    }

#pragma unroll
    for (int m = 0; m < 4; ++m) {
#pragma unroll
        for (int n = 0; n < 4; ++n) {
            const int c = nbase + wn * 64 + n * 16 + r;
#pragma unroll
            for (int j = 0; j < 4; ++j) {
                const int rr = mbase + wm * 64 + m * 16 + g * 4 + j;
                const float y = acc[m][n][j];
                if (EPI == 0) {
                    const int which = c >> 10, d = c & 1023;
                    const int b = rr >> 11, l = rr & 2047;
                    const int h = d >> 6, dd = d & 63;
                    const size_t bh = (size_t)(b * 16 + h);
                    if (which == 0) {
                        o_q[(bh * 2048 + l) * 64 + dd] = f2bf((y + bias0[d]) * 0.125f);
                    } else if (which == 1) {
                        o_k[(bh * 2048 + l) * 64 + dd] = f2bf(y + bias1[d]);
                    } else {
                        o_vt[(bh * 64 + dd) * 2048 + l] = f2bf(y + bias2[d]);
                    }
                } else {
                    o_f[(size_t)rr * 1024 + c] = y + bias0[c];
                }
            }
        }
    }
}

// ---------------- flash attention v6: R3 structure + permlane P (no P-LDS) ----------------
// grid: 1024 flat (32 q-tiles x 32 bh, XCD-swizzled). block: 128 (2 waves x 32 q-rows).

__global__ __launch_bounds__(128, 2) void attn_kernel(
    const u16* __restrict__ qb, const u16* __restrict__ kb,
    const u16* __restrict__ vtb, const float* __restrict__ bondf,
    u16* __restrict__ attnout)
{
    __shared__ u16 Ks[2][64 * 64];   // [buf][key][dk]   swizzled chunks
    __shared__ u16 Vs[2][64 * 64];   // [buf][dk][key]   swizzled chunks
    const int t = threadIdx.x;
    const int lane = t & 63, w = t >> 6;
    const int g = lane >> 4, r = lane & 15;
    const int sw = r & 7;
    const int pg = ((g & 1) << 1) | (g >> 1);   // key-chunk permutation from permlane16_swap
    const int flat = blockIdx.x;
    const int wg = (flat & 7) * 128 + (flat >> 3);
    const int bh = wg >> 5, qt = wg & 31;
    const int b = bh >> 4, h = bh & 15;
    const int q0 = qt * 64 + w * 32;
    const size_t kvBase = (size_t)bh * 2048 * 64;
    const size_t bondRow0 = ((size_t)b * 2048 + q0 + r) * 2048;   // qf adds 16*2048

    // Q as B-operand fragments: lane gives Q[q0+qf*16+r][kz*32+g*8+jj]
    bf16x8 aq[2][2];
#pragma unroll
    for (int qf = 0; qf < 2; ++qf)
#pragma unroll
        for (int kz = 0; kz < 2; ++kz)
            aq[qf][kz] = *(const bf16x8*)&qb[kvBase + (size_t)(q0 + qf * 16 + r) * 64 + kz * 32 + g * 8];

    const f32x4 zero4 = {0.f, 0.f, 0.f, 0.f};
    f32x4 o[2][4];
#pragma unroll
    for (int qf = 0; qf < 2; ++qf)
#pragma unroll
        for (int nf = 0; nf < 4; ++nf) o[qf][nf] = zero4;
    float sm[2] = {0.f, 0.f};

    // prologue: stage K/V tile 0; bond tile 0 into registers
#pragma unroll
    for (int i = 0; i < 4; ++i) {
        const int idx = i * 128 + t;
        const int row = idx >> 3, ch = idx & 7;
        const int chg = ch ^ (row & 7);
        gld16(kb + kvBase + (size_t)row * 64 + chg * 8, (char*)&Ks[0][0] + idx * 16);
        gld16(vtb + ((size_t)bh * 64 + row) * 2048 + chg * 8, (char*)&Vs[0][0] + idx * 16);
    }
    float4 bd[2][4], bdn[2][4];
#pragma unroll
    for (int qf = 0; qf < 2; ++qf)
#pragma unroll
        for (int kf = 0; kf < 4; ++kf)
            bd[qf][kf] = *(const float4*)&bondf[bondRow0 + (size_t)qf * 16 * 2048 + kf * 16 + g * 4];
    __syncthreads();

    for (int it = 0; it < 32; ++it) {
        const int cur = it & 1;
        const int kt = it * 64;
        // phase 1: issue K/V prefetch for t+1 (stays in flight through compute)
        if (it < 31) {
            const int kt2 = kt + 64;
#pragma unroll
            for (int i = 0; i < 4; ++i) {
                const int idx = i * 128 + t;
                const int row = idx >> 3, ch = idx & 7;
                const int chg = ch ^ (row & 7);
                gld16(kb + kvBase + (size_t)(kt2 + row) * 64 + chg * 8, (char*)&Ks[cur ^ 1][0] + idx * 16);
                gld16(vtb + ((size_t)bh * 64 + row) * 2048 + kt2 + chg * 8, (char*)&Vs[cur ^ 1][0] + idx * 16);
            }
            // phase 2: issue bond loads for t+1 into regs (wait lands after compute)
#pragma unroll
            for (int qf = 0; qf < 2; ++qf)
#pragma unroll
                for (int kf = 0; kf < 4; ++kf)
                    bdn[qf][kf] = *(const float4*)&bondf[bondRow0 + (size_t)qf * 16 * 2048 + kt2 + kf * 16 + g * 4];
        }

        // phase 3: QK^T for kf=0,1 (keys 0..31)
        f32x4 st[2][4];
        {
            bf16x8 kfr[2][2];
#pragma unroll
            for (int kz = 0; kz < 2; ++kz)
#pragma unroll
                for (int kf = 0; kf < 2; ++kf)
                    kfr[kz][kf] = *(const bf16x8*)((const char*)&Ks[cur][0] +
                                    (kf * 16 + r) * 128 + (((kz * 4 + g) ^ sw) * 16));
#pragma unroll
            for (int qf = 0; qf < 2; ++qf)
#pragma unroll
                for (int kf = 0; kf < 2; ++kf) st[qf][kf] = zero4;
            __builtin_amdgcn_s_setprio(1);
#pragma unroll
            for (int kz = 0; kz < 2; ++kz)
#pragma unroll
                for (int qf = 0; qf < 2; ++qf)
#pragma unroll
                    for (int kf = 0; kf < 2; ++kf)
                        st[qf][kf] = __builtin_amdgcn_mfma_f32_16x16x32_bf16(kfr[kz][kf], aq[qf][kz], st[qf][kf], 0, 0, 0);
            __builtin_amdgcn_s_setprio(0);
        }

        // phase 4: exp kf=0,1; permlane-swap into PV A-fragment ap0 (keys 0..31)
        bf16x8 ap0[2], ap1[2];
#pragma unroll
        for (int qf = 0; qf < 2; ++qf) {
            uint32_t pkl[2], pkh[2];
#pragma unroll
            for (int kf = 0; kf < 2; ++kf) {
                const float p0 = __expf(st[qf][kf][0] * bd[qf][kf].x);
                const float p1 = __expf(st[qf][kf][1] * bd[qf][kf].y);
                const float p2 = __expf(st[qf][kf][2] * bd[qf][kf].z);
                const float p3 = __expf(st[qf][kf][3] * bd[qf][kf].w);
                sm[qf] += (p0 + p1) + (p2 + p3);
                pkl[kf] = packbf(p0, p1);
                pkh[kf] = packbf(p2, p3);
            }
            plswap16(pkl[0], pkl[1]);
            plswap16(pkh[0], pkh[1]);
            union { uint32_t u[4]; bf16x8 v; } a;
            a.u[0] = pkl[0]; a.u[1] = pkh[0]; a.u[2] = pkl[1]; a.u[3] = pkh[1];
            ap0[qf] = a.v;
        }

        // phase 5: QK^T for kf=2,3
        {
            bf16x8 kfr[2][2];
#pragma unroll
            for (int kz = 0; kz < 2; ++kz)
#pragma unroll
                for (int kf = 0; kf < 2; ++kf)
                    kfr[kz][kf] = *(const bf16x8*)((const char*)&Ks[cur][0] +
                                    ((kf + 2) * 16 + r) * 128 + (((kz * 4 + g) ^ sw) * 16));
#pragma unroll
            for (int qf = 0; qf < 2; ++qf)
#pragma unroll
                for (int kf = 0; kf < 2; ++kf) st[qf][kf + 2] = zero4;
            __builtin_amdgcn_s_setprio(1);
#pragma unroll
            for (int kz = 0; kz < 2; ++kz)
#pragma unroll
                for (int qf = 0; qf < 2; ++qf)
#pragma unroll
                    for (int kf = 0; kf < 2; ++kf)
                        st[qf][kf + 2] = __builtin_amdgcn_mfma_f32_16x16x32_bf16(kfr[kz][kf], aq[qf][kz], st[qf][kf + 2], 0, 0, 0);
            __builtin_amdgcn_s_setprio(0);
        }

        // phase 6: PV kz=0 (keys 0..31; V chunk pg matches permuted key order)
        {
            bf16x8 bv_[4];
#pragma unroll
            for (int nf = 0; nf < 4; ++nf)
                bv_[nf] = *(const bf16x8*)((const char*)&Vs[cur][0] +
                            (nf * 16 + r) * 128 + ((pg ^ sw) * 16));
            __builtin_amdgcn_s_setprio(1);
#pragma unroll
            for (int qf = 0; qf < 2; ++qf)
#pragma unroll
                for (int nf = 0; nf < 4; ++nf)
                    o[qf][nf] = __builtin_amdgcn_mfma_f32_16x16x32_bf16(ap0[qf], bv_[nf], o[qf][nf], 0, 0, 0);
            __builtin_amdgcn_s_setprio(0);
        }

        // phase 7: exp kf=2,3 -> ap1 (keys 32..63)
#pragma unroll
        for (int qf = 0; qf < 2; ++qf) {
            uint32_t pkl[2], pkh[2];
#pragma unroll
            for (int kf = 0; kf < 2; ++kf) {
                const float p0 = __expf(st[qf][kf + 2][0] * bd[qf][kf + 2].x);
                const float p1 = __expf(st[qf][kf + 2][1] * bd[qf][kf + 2].y);
                const float p2 = __expf(st[qf][kf + 2][2] * bd[qf][kf + 2].z);
                const float p3 = __expf(st[qf][kf + 2][3] * bd[qf][kf + 2].w);
                sm[qf] += (p0 + p1) + (p2 + p3);
                pkl[kf] = packbf(p0, p1);
                pkh[kf] = packbf(p2, p3);
            }
            plswap16(pkl[0], pkl[1]);
            plswap16(pkh[0], pkh[1]);
            union { uint32_t u[4]; bf16x8 v; } a;
            a.u[0] = pkl[0]; a.u[1] = pkh[0]; a.u[2] = pkl[1]; a.u[3] = pkh[1];
            ap1[qf] = a.v;
        }

        // phase 8: PV kz=1 (keys 32..63)
        {
            bf16x8 bv_[4];
#pragma unroll
            for (int nf = 0; nf < 4; ++nf)
                bv_[nf] = *(const bf16x8*)((const char*)&Vs[cur][0] +
                            (nf * 16 + r) * 128 + (((4 + pg) ^ sw) * 16));
            __builtin_amdgcn_s_setprio(1);
#pragma unroll
            for (int qf = 0; qf < 2; ++qf)
#pragma unroll
                for (int nf = 0; nf < 4; ++nf)
                    o[qf][nf] = __builtin_amdgcn_mfma_f32_16x16x32_bf16(ap1[qf], bv_[nf], o[qf][nf], 0, 0, 0);
            __builtin_amdgcn_s_setprio(0);
        }

        // phase 9: rotate bond regs (forces the bond-load wait here, after compute)
        if (it < 31) {
#pragma unroll
            for (int qf = 0; qf < 2; ++qf)
#pragma unroll
                for (int kf = 0; kf < 4; ++kf)
                    bd[qf][kf] = bdn[qf][kf];
        }
        __syncthreads();
    }

    // row sums: reduce across the 4 g-groups, redistribute via width-16 shuffle
#pragma unroll
    for (int qf = 0; qf < 2; ++qf) {
        sm[qf] += __shfl_xor(sm[qf], 16, 64);
        sm[qf] += __shfl_xor(sm[qf], 32, 64);
    }
#pragma unroll
    for (int qf = 0; qf < 2; ++qf)
#pragma unroll
        for (int j = 0; j < 4; ++j) {
            const float inv = 1.f / __shfl(sm[qf], g * 4 + j, 16);
            const size_t orow = ((size_t)b * 2048 + q0 + qf * 16 + g * 4 + j) * 1024 + h * 64;
#pragma unroll
            for (int nf = 0; nf < 4; ++nf)
                attnout[orow + nf * 16 + r] = f2bf(o[qf][nf][j] * inv);
        }
}

// ---------------- launch ----------------

extern "C" void kernel_launch(void* const* d_in, const int* in_sizes, int n_in,
                              void* d_out, int out_size, void* d_ws, size_t ws_size,
                              hipStream_t stream) {
    (void)in_sizes; (void)n_in; (void)out_size; (void)ws_size;
    const float* x    = (const float*)d_in[0];
    const float* bond = (const float*)d_in[1];
    const float* Wq   = (const float*)d_in[2];
    const float* bq   = (const float*)d_in[3];
    const float* Wk   = (const float*)d_in[4];
    const float* bk   = (const float*)d_in[5];
    const float* Wv   = (const float*)d_in[6];
    const float* bv   = (const float*)d_in[7];
    const float* Wo   = (const float*)d_in[8];
    const float* bo   = (const float*)d_in[9];
    float* out = (float*)d_out;

    char* ws = (char*)d_ws;
    u16* xb      = (u16*)(ws);
    u16* wqkvt   = (u16*)(ws + 8388608);
    u16* wot     = (u16*)(ws + 14680064);
    u16* qb      = (u16*)(ws + 16777216);
    u16* kb_     = (u16*)(ws + 25165824);
    u16* vtb     = (u16*)(ws + 33554432);
    u16* attnout = (u16*)(ws + 58720256);

    dim3 tb(32, 8);
    transpose4_bf16_kernel<<<dim3(32, 32, 4), tb, 0, stream>>>(Wq, Wk, Wv, Wo, wqkvt, wot);
    cvt_bf16_kernel<<<1024, 256, 0, stream>>>(x, xb, 4194304 / 4);

    gemm128<0><<<dim3(24, 32), 256, 0, stream>>>(xb, wqkvt, bq, bk, bv, qb, kb_, vtb, nullptr);
    attn_kernel<<<dim3(1024), 128, 0, stream>>>(qb, kb_, vtb, bond, attnout);
    gemm128<1><<<dim3(8, 32), 256, 0, stream>>>(attnout, wot, bo, nullptr, nullptr,
                                                nullptr, nullptr, nullptr, out);
}